// Round 7
// baseline (7106.532 us; speedup 1.0000x reference)
//
#include <hip/hip_runtime.h>
#include <math.h>

#define B_    32
#define P_    4096
#define N_    1024
#define POS_  10
#define PP    (P_ + 2)     // padded phoneme rows (guard top/bottom)
#define NP    (N_ + 2)     // padded note rows
#define GB    8            // batches per phase-A chunk
#define NCHK  (B_ / GB)    // 4 phase-A chunks
#define TCH   256          // LSTM time chunk
#define NTCH  (N_ / TCH)   // 4 time chunks
#define CIN1P 272          // conv1 padded input channels (266 real)

typedef unsigned short u16;
typedef _Float16 h2_t __attribute__((ext_vector_type(2)));
typedef unsigned u32x4 __attribute__((ext_vector_type(4)));

// ---------------- helpers ----------------
__device__ __forceinline__ float sigmoidf_(float x) { return 1.f / (1.f + __expf(-x)); }
__device__ __forceinline__ float tanhf_(float x) {
  float t = fminf(fmaxf(x, -30.f), 30.f);
  float e = __expf(2.f * t);
  return (e - 1.f) / (e + 1.f);
}
__device__ __forceinline__ float bf2f(u16 u) { return __uint_as_float(((unsigned)u) << 16); }
__device__ __forceinline__ u16 f2bf(float f) {
  unsigned u = __float_as_uint(f);
  unsigned r = u + 0x7FFFu + ((u >> 16) & 1u);
  return (u16)(r >> 16);
}
__device__ __forceinline__ float ldA(const float* p) { return *p; }
__device__ __forceinline__ float ldA(const u16* p) { return bf2f(*p); }
__device__ __forceinline__ u16 f2h_bits(float x) {
  _Float16 hh = (_Float16)x; u16 u; __builtin_memcpy(&u, &hh, 2); return u;
}
__device__ __forceinline__ unsigned pack2h(float lo, float hi) {
  return (unsigned)f2h_bits(lo) | ((unsigned)f2h_bits(hi) << 16);
}
__device__ __forceinline__ float dot2(unsigned w, unsigned h, float acc) {
  return __builtin_amdgcn_fdot2(__builtin_bit_cast(h2_t, w), __builtin_bit_cast(h2_t, h), acc, false);
}
#define RL(v, l) ((unsigned)__builtin_amdgcn_readlane((int)(v), (l)))
// dot a 4-u32 weight quad against 4 uniform h u32s (hs0..hs3 in scope)
#define DOT4S(acc, wq) \
  acc = dot2((wq).x, hs0, acc); acc = dot2((wq).y, hs1, acc); \
  acc = dot2((wq).z, hs2, acc); acc = dot2((wq).w, hs3, acc);

#define REP24(X) X(0)X(1)X(2)X(3)X(4)X(5)X(6)X(7)X(8)X(9)X(10)X(11)X(12)X(13)X(14)X(15)X(16)X(17)X(18)X(19)X(20)X(21)X(22)X(23)
#define REP8(X)  X(0)X(1)X(2)X(3)X(4)X(5)X(6)X(7)

// ---------------- diagnostics ----------------
__global__ void fill_sentinel_kernel(float* out, int n, float v) {
  int i = blockIdx.x * 256 + threadIdx.x;
  if (i < n) out[i] = v;
}

// ---------------- zero guards ----------------
__global__ void zero_chunk_guards_kernel(float* X0c, float* X1c) {
  int cb = blockIdx.x, t = threadIdx.x;
  for (int c = t; c < CIN1P; c += 256) {
    X0c[((long)cb * PP + 0) * CIN1P + c] = 0.f;
    X0c[((long)cb * PP + PP - 1) * CIN1P + c] = 0.f;
  }
  if (t < 256) {
    X1c[((long)cb * PP + 0) * 256 + t] = 0.f;
    X1c[((long)cb * PP + PP - 1) * 256 + t] = 0.f;
  }
}
__global__ void zero_y1p_guards_kernel(u16* Y1p) {
  int b = blockIdx.x, t = threadIdx.x;
  for (int c = t; c < 512; c += 256) {
    Y1p[((long)b * NP + 0) * 512 + c] = 0;
    Y1p[((long)b * NP + NP - 1) * 512 + c] = 0;
  }
}
__global__ void zero_c3p_guards_kernel(float* C3p) {
  int b = blockIdx.x, t = threadIdx.x;
  if (t < 256) {
    C3p[((long)b * NP + 0) * 256 + t] = 0.f;
    C3p[((long)b * NP + NP - 1) * 256 + t] = 0.f;
  }
}

// ---------------- embedding (chunked) ----------------
__global__ void embed_chunk_kernel(const int* __restrict__ seq, const int* __restrict__ order,
                                   const float* __restrict__ emb, const float* __restrict__ pos_emb,
                                   float* __restrict__ X0c, int b0) {
  long i = (long)blockIdx.x * 256 + threadIdx.x;
  const long total = (long)GB * P_ * CIN1P;
  if (i >= total) return;
  int c = (int)(i % CIN1P);
  long bp = i / CIN1P;
  int p = (int)(bp % P_);
  int cb = (int)(bp / P_);
  int b = b0 + cb;
  float v = 0.f;
  if (c < 256)      v = emb[(long)seq[(long)b * P_ + p] * 256 + c];
  else if (c < 266) v = pos_emb[(long)order[(long)b * P_ + p] * POS_ + (c - 256)];
  X0c[((long)cb * PP + p + 1) * CIN1P + c] = v;
}

// ---------------- weight repacks ----------------
__global__ void repack_conv_w_kernel(const float* __restrict__ w, float* __restrict__ dst,
                                     int CinReal, int CinPad, int Cout) {
  long i = (long)blockIdx.x * 256 + threadIdx.x;
  long total = 3L * CinPad * Cout;
  if (i >= total) return;
  int k = (int)(i / Cout), co = (int)(i - (long)k * Cout);
  int rr = k / CinPad, ci = k - rr * CinPad;
  dst[i] = (ci < CinReal) ? w[((long)co * CinReal + ci) * 3 + rr] : 0.f;
}
// dense w[co(1024)][k] -> dst[k][j] with PERMUTED column j: co = R(j) = (j&3)*256 + (j>>2)
__global__ void repack_dense_w_perm_kernel(const float* __restrict__ w, float* __restrict__ dst,
                                           int CinReal, int Kpad) {
  long i = (long)blockIdx.x * 256 + threadIdx.x;
  if (i >= (long)Kpad * 1024) return;
  int k = (int)(i >> 10), j = (int)(i & 1023);
  int co = (j & 3) * 256 + (j >> 2);
  dst[i] = (k < CinReal) ? w[(long)co * CinReal + k] : 0.f;
}
// Whh k<192 slice -> register-resident quads: Wv[((d*2+rb)*24+kq)*512 + j]
// row(j,rb): R = (j&3)*256 + (j>>2) + rb*128; quad q covers k = kq*8+2q, +1
__global__ void repack_whh_reg_kernel(const float* __restrict__ whh, uint4* __restrict__ Wv) {
  long i = (long)blockIdx.x * 256 + threadIdx.x;
  if (i >= 49152) return;
  int j = (int)(i & 511);
  int t = (int)(i >> 9);
  int kq = t % 24, rb = (t / 24) & 1, d = t / 48;
  int R = (j & 3) * 256 + (j >> 2) + rb * 128;
  const float* wr = whh + ((long)d * 1024 + R) * 256;
  uint4 o; unsigned* op = (unsigned*)&o;
#pragma unroll
  for (int q = 0; q < 4; q++) {
    int k = kq * 8 + 2 * q;
    op[q] = pack2h(wr[k], wr[k + 1]);
  }
  Wv[i] = o;
}
// Whh k in [192,256) -> LDS-resident, LINEAR-LANE layout:
// Ws[d*8192 + rb*4096 + i2*512 + j]; R = (j&3)*256 + (j>>2) + rb*128; quad i2 covers k=192+i2*8+2q
__global__ void repack_whh_lds_kernel(const float* __restrict__ whh, uint4* __restrict__ Ws) {
  long i = (long)blockIdx.x * 256 + threadIdx.x;
  if (i >= 16384) return;
  int d = (int)(i >> 13);
  int a = (int)(i & 8191);
  int rb = a >> 12;
  int rem = a & 4095;
  int i2 = rem >> 9, j = rem & 511;
  int R = (j & 3) * 256 + (j >> 2) + rb * 128;
  const float* wr = whh + ((long)d * 1024 + R) * 256;
  uint4 o; unsigned* op = (unsigned*)&o;
#pragma unroll
  for (int q = 0; q < 4; q++) {
    int k = 192 + i2 * 8 + 2 * q;
    op[q] = pack2h(wr[k], wr[k + 1]);
  }
  Ws[i] = o;
}
// permuted bias sum: dst[d*1024 + j] = a[d*1024 + R(j)] + b[d*1024 + R(j)]
__global__ void bias_sum_perm_kernel(const float* __restrict__ a, const float* __restrict__ b,
                                     float* __restrict__ dst) {
  int i = blockIdx.x * 256 + threadIdx.x;
  if (i >= 2048) return;
  int d = i >> 10, j = i & 1023;
  int R = (j & 3) * 256 + (j >> 2);
  dst[i] = a[d * 1024 + R] + b[d * 1024 + R];
}
__global__ void repack_conv4_w_kernel(const float* __restrict__ w, float* __restrict__ dst) {
  int i = blockIdx.x * 256 + threadIdx.x;
  if (i < 768) { int r = i >> 8, ci = i & 255; dst[i] = w[ci * 3 + r]; }
}

// ---------------- rows-GEMM: C = A_rows @ Bm[Kpad x N] + bias ----------------
// As is column-XOR-swizzled to kill the 4-way write bank conflict.
template <typename AT>
__global__ __launch_bounds__(256) void gemm_rows_kernel(
    const AT* __restrict__ A, const float* __restrict__ Bm,
    const float* __restrict__ bias, float* __restrict__ C,
    int N, int Kpad, int Mb,
    long aBatchStride, int aRowStride,
    long cBatchStride, int cRowStride,
    int relu) {
  __shared__ float As[16][64];   // [k][row^swz]
  __shared__ float Bs[16][64];   // [k][col]
  int tid = threadIdx.x;
  int row0 = blockIdx.x * 64;
  int col0 = blockIdx.y * 64;
  int tx = tid & 15, ty = tid >> 4;
  int ar = tid >> 2, akq = (tid & 3) * 4;
  int swzA = (tid & 3) << 3;            // == ((k>>2)&3)<<3 for k = akq+q
  int arS = ar ^ swzA;
  int grow = row0 + ar;
  int b_ = grow / Mb, m_ = grow - b_ * Mb;
  const AT* arow = A + (long)b_ * aBatchStride + (long)m_ * aRowStride;
  int kb = tid >> 4, nq = (tid & 15) * 4;
  const float* bptr = Bm + (long)kb * N + col0 + nq;

  float acc[4][4];
#pragma unroll
  for (int i = 0; i < 4; i++)
#pragma unroll
    for (int j = 0; j < 4; j++) acc[i][j] = 0.f;

  for (int k0 = 0; k0 < Kpad; k0 += 16) {
    float a0 = ldA(arow + k0 + akq + 0);
    float a1 = ldA(arow + k0 + akq + 1);
    float a2 = ldA(arow + k0 + akq + 2);
    float a3 = ldA(arow + k0 + akq + 3);
    float4 b4 = *(const float4*)(bptr + (long)k0 * N);
    __syncthreads();
    As[akq + 0][arS] = a0;
    As[akq + 1][arS] = a1;
    As[akq + 2][arS] = a2;
    As[akq + 3][arS] = a3;
    *(float4*)&Bs[kb][nq] = b4;
    __syncthreads();
#pragma unroll
    for (int kk = 0; kk < 16; ++kk) {
      float4 av = *(const float4*)&As[kk][(ty * 4) ^ (((kk >> 2) & 3) << 3)];
      float4 bv = *(const float4*)&Bs[kk][tx * 4];
      acc[0][0] += av.x * bv.x; acc[0][1] += av.x * bv.y; acc[0][2] += av.x * bv.z; acc[0][3] += av.x * bv.w;
      acc[1][0] += av.y * bv.x; acc[1][1] += av.y * bv.y; acc[1][2] += av.y * bv.z; acc[1][3] += av.y * bv.w;
      acc[2][0] += av.z * bv.x; acc[2][1] += av.z * bv.y; acc[2][2] += av.z * bv.z; acc[2][3] += av.z * bv.w;
      acc[3][0] += av.w * bv.x; acc[3][1] += av.w * bv.y; acc[3][2] += av.w * bv.z; acc[3][3] += av.w * bv.w;
    }
  }
  float4 bb = *(const float4*)&bias[col0 + tx * 4];
#pragma unroll
  for (int i = 0; i < 4; i++) {
    int gr = row0 + ty * 4 + i;
    int b2 = gr / Mb, m2 = gr - b2 * Mb;
    float4 o;
    o.x = acc[i][0] + bb.x; o.y = acc[i][1] + bb.y; o.z = acc[i][2] + bb.z; o.w = acc[i][3] + bb.w;
    if (relu) { o.x = fmaxf(o.x, 0.f); o.y = fmaxf(o.y, 0.f); o.z = fmaxf(o.z, 0.f); o.w = fmaxf(o.w, 0.f); }
    *(float4*)(C + (long)b2 * cBatchStride + (long)m2 * cRowStride + col0 + tx * 4) = o;
  }
}

// ---------------- note-segment scan: parallel runs-scan ----------------
__global__ __launch_bounds__(256) void seg_scan_kernel(const int* __restrict__ seq,
                                int* __restrict__ nstart, int* __restrict__ nlen) {
  __shared__ unsigned char v[P_];
  __shared__ int sc[2][256];
  int b = blockIdx.x, tid = threadIdx.x;
  for (int i = tid; i < P_; i += 256) {
    int s = seq[(long)b * P_ + i];
    v[i] = (s > 1 && i != P_ - 1) ? 1 : 0;   // last position never included
  }
  for (int n = tid; n < N_; n += 256) { nstart[b * N_ + n] = 0; nlen[b * N_ + n] = 0; }
  __syncthreads();
  int base = tid << 4;
  int c = 0;
#pragma unroll
  for (int i = 0; i < 16; i++) {
    int p = base + i;
    int val = v[p];
    int prev = p ? v[p - 1] : 0;
    c += val & (prev ^ 1);
  }
  sc[0][tid] = c;
  __syncthreads();
  int cur = 0;
  for (int d = 1; d < 256; d <<= 1) {
    int x = sc[cur][tid];
    if (tid >= d) x += sc[cur][tid - d];
    sc[cur ^ 1][tid] = x;
    cur ^= 1;
    __syncthreads();
  }
  int sg = tid ? sc[cur][tid - 1] : 0;   // exclusive prefix = first seg id in my chunk
  for (int i = 0; i < 16; i++) {
    int p = base + i;
    int val = v[p];
    int prev = p ? v[p - 1] : 0;
    if (val && !prev) {
      if (sg < N_) {
        int len = 0, q = p;
        while (q < P_ && v[q]) { len++; q++; }
        nstart[b * N_ + sg] = p;
        nlen[b * N_ + sg] = len;
      }
      sg++;
    }
  }
}

// ---------------- segment mean + enc (bf16, stride 272) ----------------
__global__ __launch_bounds__(256) void agg_enc_kernel(
    const float* __restrict__ X2c, const int* __restrict__ nstart, const int* __restrict__ nlen,
    const float* __restrict__ dur, u16* __restrict__ enc, int b0) {
  int n = blockIdx.x, gb = blockIdx.y;
  int b = b0 + gb;
  int d = threadIdx.x;
  int len = nlen[b * N_ + n], st = nstart[b * N_ + n];
  float acc = 0.f;
  for (int i = 0; i < len; i++) acc += X2c[((long)gb * PP + st + 1 + i) * CIN1P + d];
  float m = (len > 0) ? acc / (float)len : 0.f;
  long e = ((long)b * N_ + n) * 272;
  enc[e + d] = f2bf(m);
  if (d == 0) {
    float dd = dur[b * N_ + n];
    enc[e + 256] = f2bf(dd);
    enc[e + 257] = f2bf(1.f / (dd + 1.f));
  }
  if (d >= 2 && d < 16) enc[e + 256 + d] = 0;  // zero tail 258..271
}

// ---------------- LSTM recurrence v6: readlane h-broadcast (off the LDS pipe) ----------------
// 64 WGs (chain = dir*32+b), 512 threads; thread owns rows j=tid and j=tid+512.
// Z columns PRE-PERMUTED (col j = logical row R(j)) -> coalesced z loads.
// Rounds 3-6 lesson: the kernel was LDS-ISSUE-PIPE bound (384 ds_read_b128/step/CU
// ~= 4600 cyc, matching 470us). Fix: h is no longer broadcast via 32 wave-uniform
// b128 LDS reads per thread; instead each wave loads h DISTRIBUTED (lane l holds
// h-u32 l and 64+l -- just 2 ds_read_b32/wave) and extracts pairs with
// v_readlane (VALU pipe, parallel across 4 SIMDs) feeding v_dot2's uniform operand.
// LDS instrs/step/CU: 384 -> ~150 (128 weight b128 reads remain).
#define REC_LDS_BYTES (131072 + 4096 + 1024)
__global__ __attribute__((amdgpu_waves_per_eu(2, 2))) __launch_bounds__(512)
void lstm_rec2_kernel(
    const float* __restrict__ Z,      // [2][32][TCH][1024] fp32, permuted cols
    const u32x4* __restrict__ Wv,     // [2][2][24][512] fp16 quads (k<192)
    const u32x4* __restrict__ Ws,     // [2][2][8][512] fp16 quads (k>=192)
    float* __restrict__ state,        // [64][2][256]
    u16* __restrict__ Y, int yRowsPerB, int yPad, int r) {
  extern __shared__ char smem[];
  u32x4* WL = (u32x4*)smem;                              // 8192 quads
  float* zb = (float*)(smem + 131072);                   // 1024 f32
  u16*   hb = (u16*)(smem + 131072 + 4096);              // 256 fp16
  const unsigned* hbu = (const unsigned*)hb;             // 128 u32 (fp16 pairs)

  int chain = blockIdx.x;
  int d = chain >> 5, b = chain & 31;
  int tid = threadIdx.x;
  int lane = tid & 63;
  const float* Zb = Z + (long)(d * 32 + b) * (TCH * 1024);

  // stage LDS weights (linear copy; layout pre-baked by repack)
  for (int iq = 0; iq < 16; ++iq) {
    int q = iq * 512 + tid;
    WL[q] = Ws[(long)d * 8192 + q];
  }
  // load register weights into NAMED variables (48 x u32x4), pinned against remat
  const u32x4* WvD = Wv + (long)d * 2 * 24 * 512;
#define DECLW(i) u32x4 wA##i, wB##i;
  REP24(DECLW)
#undef DECLW
#define LOADW(i) wA##i = WvD[(i) * 512 + tid]; wB##i = WvD[(24 + (i)) * 512 + tid];
  REP24(LOADW)
#undef LOADW
#define PINW(i) asm volatile("" : "+v"(wA##i), "+v"(wB##i));
  REP24(PINW)
#undef PINW

  float h_reg = 0.f, c_reg = 0.f;
  if (tid < 256) {
    if (r > 0) {
      h_reg = state[(chain * 2 + 0) * 256 + tid];
      c_reg = state[(chain * 2 + 1) * 256 + tid];
    }
    hb[tid] = f2h_bits(h_reg);
  }
  __syncthreads();

  int t0 = (d == 0) ? r * TCH : (NTCH - 1 - r) * TCH;
  int tcf = d ? (TCH - 1) : 0;
  float preA = Zb[(long)tcf * 1024 + tid];
  float preB = Zb[(long)tcf * 1024 + 512 + tid];

  for (int tt = 0; tt < TCH; ++tt) {
    // distributed h pickup: lane l holds h-u32 l (hd0) and 64+l (hd1)
    unsigned hd0 = hbu[lane];
    unsigned hd1 = hbu[64 + lane];
    float accA = preA, accB = preB;
    if (tt + 1 < TCH) {                       // prefetch next step's z (coalesced)
      int tc2 = d ? (TCH - 2 - tt) : (tt + 1);
      preA = Zb[(long)tc2 * 1024 + tid];
      preB = Zb[(long)tc2 * 1024 + 512 + tid];
    }
    // k<192: register weights; h pairs via readlane (uniform -> dot2 SGPR operand)
#define MACW(i) { unsigned hs0, hs1, hs2, hs3; \
    if ((i) < 16) { hs0 = RL(hd0, 4*(i)+0); hs1 = RL(hd0, 4*(i)+1); \
                    hs2 = RL(hd0, 4*(i)+2); hs3 = RL(hd0, 4*(i)+3); } \
    else          { hs0 = RL(hd1, 4*((i)-16)+0); hs1 = RL(hd1, 4*((i)-16)+1); \
                    hs2 = RL(hd1, 4*((i)-16)+2); hs3 = RL(hd1, 4*((i)-16)+3); } \
    DOT4S(accA, wA##i); DOT4S(accB, wB##i); }
    REP24(MACW)
#undef MACW
    // k in [192,256): LDS weights (lane-linear, conflict-free), h via readlane
#define MACL(i) { unsigned hs0 = RL(hd1, 32+4*(i)+0), hs1 = RL(hd1, 32+4*(i)+1), \
                           hs2 = RL(hd1, 32+4*(i)+2), hs3 = RL(hd1, 32+4*(i)+3); \
                  u32x4 qa = WL[(i) * 512 + tid]; \
                  u32x4 qb = WL[4096 + (i) * 512 + tid]; \
                  DOT4S(accA, qa); DOT4S(accB, qb); }
    REP8(MACL)
#undef MACL
    zb[tid] = accA;
    zb[tid + 512] = accB;
    __syncthreads();
    int tcur = d ? (TCH - 1 - tt) : tt;
    if (tid < 256) {
      float4 z4 = *(const float4*)&zb[tid * 4];   // (i,f,g,o) of unit tid
      float ig = sigmoidf_(z4.x), fg = sigmoidf_(z4.y);
      float gg = tanhf_(z4.z), og = sigmoidf_(z4.w);
      c_reg = fg * c_reg + ig * gg;
      float h = og * tanhf_(c_reg);
      h_reg = h;
      hb[tid] = f2h_bits(h);
      Y[((long)b * yRowsPerB + t0 + tcur + yPad) * 512 + d * 256 + tid] = f2bf(h);
    }
    __syncthreads();
  }
  if (r != NTCH - 1 && tid < 256) {
    state[(chain * 2 + 0) * 256 + tid] = h_reg;
    state[(chain * 2 + 1) * 256 + tid] = c_reg;
  }
}

// ---------------- final conv (Cout=1): wave per row ----------------
__global__ __launch_bounds__(256) void conv4_kernel(
    const float* __restrict__ C3p, const float* __restrict__ w,
    const float* __restrict__ b2, float* __restrict__ out) {
  int row = blockIdx.x * 4 + (threadIdx.x >> 6);
  int lane = threadIdx.x & 63;
  int b = row >> 10, t = row & (N_ - 1);
  const float* a = C3p + ((long)b * NP + t) * 256;
  float acc = 0.f;
  for (int k = lane; k < 768; k += 64) acc += a[k] * w[k];
  for (int off = 32; off; off >>= 1) acc += __shfl_down(acc, off, 64);
  if (lane == 0) out[row] = acc + b2[0];
}

// ---------------- host launcher ----------------
extern "C" void kernel_launch(void* const* d_in, const int* in_sizes, int n_in,
                              void* d_out, int out_size, void* d_ws, size_t ws_size,
                              hipStream_t stream) {
  const float* dur     = (const float*)d_in[0];
  const int*   seq     = (const int*)d_in[1];
  const int*   order   = (const int*)d_in[2];
  const float* emb     = (const float*)d_in[3];
  const float* pos_emb = (const float*)d_in[4];
  const float* mix_w1  = (const float*)d_in[5];
  const float* mix_b1  = (const float*)d_in[6];
  const float* mix_w2  = (const float*)d_in[7];
  const float* mix_b2  = (const float*)d_in[8];
  const float* wih0    = (const float*)d_in[9];
  const float* whh0    = (const float*)d_in[10];
  const float* bih0    = (const float*)d_in[11];
  const float* bhh0    = (const float*)d_in[12];
  const float* wih1    = (const float*)d_in[13];
  const float* whh1    = (const float*)d_in[14];
  const float* bih1    = (const float*)d_in[15];
  const float* bhh1    = (const float*)d_in[16];
  const float* cnn_w1  = (const float*)d_in[17];
  const float* cnn_b1  = (const float*)d_in[18];
  const float* cnn_w2  = (const float*)d_in[19];
  const float* cnn_b2  = (const float*)d_in[20];
  float* out = (float*)d_out;
  float* ws = (float*)d_ws;

  // opt-in to 136 KB dynamic LDS for the rec kernel (config call; capture-safe)
  (void)hipFuncSetAttribute((const void*)lstm_rec2_kernel,
                            hipFuncAttributeMaxDynamicSharedMemorySize, REC_LDS_BYTES);

  // ---- workspace layout (float units, 16-aligned) ----
  const long X0C_E = (long)GB * PP * CIN1P;
  const long X1C_E = (long)GB * PP * 256;
  const long Z_E   = 2L * B_ * TCH * 1024;
  const long C3P_E = (long)B_ * NP * 256;
  long region = X0C_E + X1C_E;
  if (Z_E > region) region = Z_E;
  if (C3P_E > region) region = C3P_E;

  long off = 0;
  auto alloc = [&](long n) { long ret = off; off += (n + 15) & ~15L; return ret; };
  long o_region = alloc(region);
  long o_enc    = alloc(((long)B_ * N_ * 272 + 1) / 2);   // bf16
  long o_Y0     = alloc(((long)B_ * N_ * 512 + 1) / 2);   // bf16
  long o_Y1p    = alloc(((long)B_ * NP * 512 + 1) / 2);   // bf16
  long o_W1r    = alloc(3L * CIN1P * 256);
  long o_W2r    = alloc(3L * 256 * 256);
  long o_Wc1r   = alloc(3L * 512 * 256);
  long o_Wc2r   = alloc(768);
  long o_Wih0r  = alloc(2L * 272 * 1024);
  long o_Wih1r  = alloc(2L * 512 * 1024);
  long o_Wv0    = alloc(49152L * 4);   // u32x4 quads (fp16), layer0
  long o_Ws0    = alloc(16384L * 4);
  long o_Wv1    = alloc(49152L * 4);   // layer1
  long o_Ws1    = alloc(16384L * 4);
  long o_bs0    = alloc(2048);
  long o_bs1    = alloc(2048);
  long o_state  = alloc(64L * 2 * 256);
  long o_nst    = alloc((long)B_ * N_);
  long o_nln    = alloc((long)B_ * N_);

  if ((size_t)(off * 4) > ws_size) {
    float v = -(1000.0f + (float)(ws_size >> 20));
    fill_sentinel_kernel<<<(out_size + 255) / 256, 256, 0, stream>>>(out, out_size, v);
    return;
  }

  float* X0c  = ws + o_region;
  float* X1c  = ws + o_region + X0C_E;
  float* Z    = ws + o_region;              // alias (after phase A)
  float* C3p  = ws + o_region;              // alias (after recs)
  u16*   enc  = (u16*)(ws + o_enc);
  u16*   Y0   = (u16*)(ws + o_Y0);
  u16*   Y1p  = (u16*)(ws + o_Y1p);
  float* W1r  = ws + o_W1r;
  float* W2r  = ws + o_W2r;
  float* Wc1r = ws + o_Wc1r;
  float* Wc2r = ws + o_Wc2r;
  float* Wih0r = ws + o_Wih0r;
  float* Wih1r = ws + o_Wih1r;
  uint4* Wv0  = (uint4*)(ws + o_Wv0);
  uint4* Ws0  = (uint4*)(ws + o_Ws0);
  uint4* Wv1  = (uint4*)(ws + o_Wv1);
  uint4* Ws1  = (uint4*)(ws + o_Ws1);
  float* bs0  = ws + o_bs0;
  float* bs1  = ws + o_bs1;
  float* state = ws + o_state;
  int* nstart = (int*)(ws + o_nst);
  int* nlen   = (int*)(ws + o_nln);

  // ---- repacks / setup ----
  zero_chunk_guards_kernel<<<GB, 256, 0, stream>>>(X0c, X1c);
  zero_y1p_guards_kernel<<<B_, 256, 0, stream>>>(Y1p);
  repack_conv_w_kernel<<<(int)((3L * CIN1P * 256 + 255) / 256), 256, 0, stream>>>(mix_w1, W1r, 266, CIN1P, 256);
  repack_conv_w_kernel<<<(int)((3L * 256 * 256 + 255) / 256), 256, 0, stream>>>(mix_w2, W2r, 256, 256, 256);
  repack_conv_w_kernel<<<(int)((3L * 512 * 256 + 255) / 256), 256, 0, stream>>>(cnn_w1, Wc1r, 512, 512, 256);
  repack_conv4_w_kernel<<<3, 256, 0, stream>>>(cnn_w2, Wc2r);
  for (int d = 0; d < 2; d++) {
    repack_dense_w_perm_kernel<<<(272 * 1024 + 255) / 256, 256, 0, stream>>>(
        wih0 + (long)d * 1024 * 258, Wih0r + (long)d * 272 * 1024, 258, 272);
    repack_dense_w_perm_kernel<<<(512 * 1024 + 255) / 256, 256, 0, stream>>>(
        wih1 + (long)d * 1024 * 512, Wih1r + (long)d * 512 * 1024, 512, 512);
  }
  repack_whh_reg_kernel<<<192, 256, 0, stream>>>(whh0, Wv0);
  repack_whh_lds_kernel<<<64, 256, 0, stream>>>(whh0, Ws0);
  repack_whh_reg_kernel<<<192, 256, 0, stream>>>(whh1, Wv1);
  repack_whh_lds_kernel<<<64, 256, 0, stream>>>(whh1, Ws1);
  bias_sum_perm_kernel<<<8, 256, 0, stream>>>(bih0, bhh0, bs0);
  bias_sum_perm_kernel<<<8, 256, 0, stream>>>(bih1, bhh1, bs1);
  seg_scan_kernel<<<B_, 256, 0, stream>>>(seq, nstart, nlen);

  // ---- phase A: embed -> conv1 -> conv2 -> aggregate (8-batch chunks) ----
  for (int ch = 0; ch < NCHK; ch++) {
    int b0 = ch * GB;
    long total = (long)GB * P_ * CIN1P;
    embed_chunk_kernel<<<(int)((total + 255) / 256), 256, 0, stream>>>(seq, order, emb, pos_emb, X0c, b0);
    gemm_rows_kernel<float><<<dim3(GB * P_ / 64, 4), 256, 0, stream>>>(
        X0c, W1r, mix_b1, X1c + 256,
        256, 3 * CIN1P, P_, (long)PP * CIN1P, CIN1P, (long)PP * 256, 256, 1);
    gemm_rows_kernel<float><<<dim3(GB * P_ / 64, 4), 256, 0, stream>>>(
        X1c, W2r, mix_b2, X0c + CIN1P,
        256, 768, P_, (long)PP * 256, 256, (long)PP * CIN1P, CIN1P, 0);
    agg_enc_kernel<<<dim3(N_, GB), 256, 0, stream>>>(X0c, nstart, nlen, dur, enc, b0);
  }

  // ---- LSTM layers (time-chunked Z, GEMM + CU-resident rec) ----
  const long ZD = (long)B_ * TCH * 1024;
  for (int layer = 0; layer < 2; layer++) {
    const u16*  Xl   = (layer == 0) ? enc : Y0;
    int         xstr = (layer == 0) ? 272 : 512;
    int         Kp   = (layer == 0) ? 272 : 512;
    const float* Wih = (layer == 0) ? Wih0r : Wih1r;
    long        WihD = (layer == 0) ? (long)272 * 1024 : (long)512 * 1024;
    const float* bsl = (layer == 0) ? bs0 : bs1;
    const u32x4* Wv  = (const u32x4*)((layer == 0) ? Wv0 : Wv1);
    const u32x4* Wsp = (const u32x4*)((layer == 0) ? Ws0 : Ws1);
    u16*        Yl   = (layer == 0) ? Y0 : Y1p;
    int         yRows = (layer == 0) ? N_ : NP;
    int         yPad  = (layer == 0) ? 0 : 1;
    for (int r = 0; r < NTCH; r++) {
      for (int d = 0; d < 2; d++) {
        int t0 = (d == 0) ? r * TCH : (NTCH - 1 - r) * TCH;
        gemm_rows_kernel<u16><<<dim3(B_ * TCH / 64, 16), 256, 0, stream>>>(
            Xl + (long)t0 * xstr, Wih + (long)d * WihD, bsl + d * 1024, Z + d * ZD,
            1024, Kp, TCH, (long)N_ * xstr, xstr, (long)TCH * 1024, 1024, 0);
      }
      lstm_rec2_kernel<<<64, 512, REC_LDS_BYTES, stream>>>(Z, Wv, Wsp, state, Yl, yRows, yPad, r);
    }
  }

  // ---- head: conv(relu) K=1536 exact, then 1-channel conv ----
  zero_c3p_guards_kernel<<<B_, 256, 0, stream>>>(C3p);
  gemm_rows_kernel<u16><<<dim3(B_ * N_ / 64, 4), 256, 0, stream>>>(
      Y1p, Wc1r, cnn_b1, C3p + 256,
      256, 1536, N_, (long)NP * 512, 512, (long)NP * 256, 256, 1);
  conv4_kernel<<<B_ * N_ / 4, 256, 0, stream>>>(C3p, Wc2r, cnn_b2, out);
}

// Round 8
// 6572.570 us; speedup vs baseline: 1.0812x; 1.0812x over previous
//
#include <hip/hip_runtime.h>
#include <math.h>

#define B_    32
#define P_    4096
#define N_    1024
#define POS_  10
#define PP    (P_ + 2)     // padded phoneme rows (guard top/bottom)
#define NP    (N_ + 2)     // padded note rows
#define GB    8            // batches per phase-A chunk
#define NCHK  (B_ / GB)    // 4 phase-A chunks
#define TCH   256          // LSTM time chunk
#define NTCH  (N_ / TCH)   // 4 time chunks
#define X0S   280          // X0b row stride (bf16): K_conv1 = 2*280+272 = 832 (mult of 32)
#define ENCS  288          // enc row stride (bf16): K mult of 32

typedef unsigned short u16;
typedef _Float16 h2_t __attribute__((ext_vector_type(2)));
typedef unsigned u32x4 __attribute__((ext_vector_type(4)));
typedef short s16x8 __attribute__((ext_vector_type(8)));     // 8 bf16 (4 VGPRs)
typedef float f32x4 __attribute__((ext_vector_type(4)));     // MFMA acc

// ---------------- helpers ----------------
__device__ __forceinline__ float sigmoidf_(float x) { return 1.f / (1.f + __expf(-x)); }
__device__ __forceinline__ float tanhf_(float x) {
  float t = fminf(fmaxf(x, -30.f), 30.f);
  float e = __expf(2.f * t);
  return (e - 1.f) / (e + 1.f);
}
__device__ __forceinline__ float bf2f(u16 u) { return __uint_as_float(((unsigned)u) << 16); }
__device__ __forceinline__ u16 f2bf(float f) {
  unsigned u = __float_as_uint(f);
  unsigned r = u + 0x7FFFu + ((u >> 16) & 1u);
  return (u16)(r >> 16);
}
__device__ __forceinline__ u16 f2h_bits(float x) {
  _Float16 hh = (_Float16)x; u16 u; __builtin_memcpy(&u, &hh, 2); return u;
}
__device__ __forceinline__ unsigned pack2h(float lo, float hi) {
  return (unsigned)f2h_bits(lo) | ((unsigned)f2h_bits(hi) << 16);
}
__device__ __forceinline__ float dot2(unsigned w, unsigned h, float acc) {
  return __builtin_amdgcn_fdot2(__builtin_bit_cast(h2_t, w), __builtin_bit_cast(h2_t, h), acc, false);
}
#define DOT4(acc, wq, hq) \
  acc = dot2((wq).x, (hq).x, acc); acc = dot2((wq).y, (hq).y, acc); \
  acc = dot2((wq).z, (hq).z, acc); acc = dot2((wq).w, (hq).w, acc);

#define REP24(X) X(0)X(1)X(2)X(3)X(4)X(5)X(6)X(7)X(8)X(9)X(10)X(11)X(12)X(13)X(14)X(15)X(16)X(17)X(18)X(19)X(20)X(21)X(22)X(23)
#define REP8(X)  X(0)X(1)X(2)X(3)X(4)X(5)X(6)X(7)

__device__ __forceinline__ void stc(float* p, float v) { *p = v; }
__device__ __forceinline__ void stc(u16* p, float v)   { *p = f2bf(v); }

// ---------------- diagnostics ----------------
__global__ void fill_sentinel_kernel(float* out, int n, float v) {
  int i = blockIdx.x * 256 + threadIdx.x;
  if (i < n) out[i] = v;
}

// ---------------- zero guards ----------------
__global__ void zero_bf_guards_kernel(u16* X0b, u16* X1b) {
  int cb = blockIdx.x, t = threadIdx.x;
  for (int c = t; c < X0S; c += 256) {
    X0b[((long)cb * PP + 0) * X0S + c] = 0;
    X0b[((long)cb * PP + PP - 1) * X0S + c] = 0;
  }
  if (t < 256) {
    X1b[((long)cb * PP + 0) * 256 + t] = 0;
    X1b[((long)cb * PP + PP - 1) * 256 + t] = 0;
  }
}
__global__ void zero_y1p_guards_kernel(u16* Y1p) {
  int b = blockIdx.x, t = threadIdx.x;
  for (int c = t; c < 512; c += 256) {
    Y1p[((long)b * NP + 0) * 512 + c] = 0;
    Y1p[((long)b * NP + NP - 1) * 512 + c] = 0;
  }
}
__global__ void zero_c3p_guards_kernel(float* C3p) {
  int b = blockIdx.x, t = threadIdx.x;
  if (t < 256) {
    C3p[((long)b * NP + 0) * 256 + t] = 0.f;
    C3p[((long)b * NP + NP - 1) * 256 + t] = 0.f;
  }
}

// ---------------- embedding (chunked, bf16 out, stride 280) ----------------
__global__ void embed_bf16_kernel(const int* __restrict__ seq, const int* __restrict__ order,
                                  const float* __restrict__ emb, const float* __restrict__ pos_emb,
                                  u16* __restrict__ X0b, int b0) {
  long i = (long)blockIdx.x * 256 + threadIdx.x;
  const long total = (long)GB * P_ * X0S;
  if (i >= total) return;
  int c = (int)(i % X0S);
  long bp = i / X0S;
  int p = (int)(bp % P_);
  int cb = (int)(bp / P_);
  int b = b0 + cb;
  float v = 0.f;
  if (c < 256)      v = emb[(long)seq[(long)b * P_ + p] * 256 + c];
  else if (c < 266) v = pos_emb[(long)order[(long)b * P_ + p] * POS_ + (c - 256)];
  X0b[((long)cb * PP + p + 1) * X0S + c] = f2bf(v);
}

// ---------------- weight repacks ----------------
// conv w[co][ci][3] -> Bt[co][Kpad] bf16, k = r*strideA + ci; optional lo residual
__global__ void repack_conv_bt_kernel(const float* __restrict__ w, u16* __restrict__ hi,
                                      u16* __restrict__ lo, int CinReal, int strideA,
                                      int Kpad, int Cout) {
  long i = (long)blockIdx.x * 256 + threadIdx.x;
  if (i >= (long)Cout * Kpad) return;
  int co = (int)(i / Kpad), k = (int)(i - (long)co * Kpad);
  int r = k / strideA, ci = k - r * strideA;
  float v = (r < 3 && ci < CinReal) ? w[((long)co * CinReal + ci) * 3 + r] : 0.f;
  u16 h = f2bf(v);
  hi[i] = h;
  if (lo) lo[i] = f2bf(v - bf2f(h));
}
// dense w[co(1024)][k] -> Bt[j][Kpad] bf16 (hi+lo), PERMUTED: co = R(j)=(j&3)*256+(j>>2)
__global__ void repack_dense_bt_kernel(const float* __restrict__ w, u16* __restrict__ hi,
                                       u16* __restrict__ lo, int CinReal, int Kpad) {
  long i = (long)blockIdx.x * 256 + threadIdx.x;
  if (i >= 1024L * Kpad) return;
  int j = (int)(i / Kpad), k = (int)(i - (long)j * Kpad);
  int co = (j & 3) * 256 + (j >> 2);
  float v = (k < CinReal) ? w[(long)co * CinReal + k] : 0.f;
  u16 h = f2bf(v);
  hi[i] = h;
  lo[i] = f2bf(v - bf2f(h));
}
// Whh k<192 slice -> register-resident quads (unchanged from r6)
__global__ void repack_whh_reg_kernel(const float* __restrict__ whh, uint4* __restrict__ Wv) {
  long i = (long)blockIdx.x * 256 + threadIdx.x;
  if (i >= 49152) return;
  int j = (int)(i & 511);
  int t = (int)(i >> 9);
  int kq = t % 24, rb = (t / 24) & 1, d = t / 48;
  int R = (j & 3) * 256 + (j >> 2) + rb * 128;
  const float* wr = whh + ((long)d * 1024 + R) * 256;
  uint4 o; unsigned* op = (unsigned*)&o;
#pragma unroll
  for (int q = 0; q < 4; q++) {
    int k = kq * 8 + 2 * q;
    op[q] = pack2h(wr[k], wr[k + 1]);
  }
  Wv[i] = o;
}
__global__ void repack_whh_lds_kernel(const float* __restrict__ whh, uint4* __restrict__ Ws) {
  long i = (long)blockIdx.x * 256 + threadIdx.x;
  if (i >= 16384) return;
  int d = (int)(i >> 13);
  int a = (int)(i & 8191);
  int rb = a >> 12;
  int rem = a & 4095;
  int i2 = rem >> 9, j = rem & 511;
  int R = (j & 3) * 256 + (j >> 2) + rb * 128;
  const float* wr = whh + ((long)d * 1024 + R) * 256;
  uint4 o; unsigned* op = (unsigned*)&o;
#pragma unroll
  for (int q = 0; q < 4; q++) {
    int k = 192 + i2 * 8 + 2 * q;
    op[q] = pack2h(wr[k], wr[k + 1]);
  }
  Ws[i] = o;
}
__global__ void bias_sum_perm_kernel(const float* __restrict__ a, const float* __restrict__ b,
                                     float* __restrict__ dst) {
  int i = blockIdx.x * 256 + threadIdx.x;
  if (i >= 2048) return;
  int d = i >> 10, j = i & 1023;
  int R = (j & 3) * 256 + (j >> 2);
  dst[i] = a[d * 1024 + R] + b[d * 1024 + R];
}
__global__ void repack_conv4_w_kernel(const float* __restrict__ w, float* __restrict__ dst) {
  int i = blockIdx.x * 256 + threadIdx.x;
  if (i < 768) { int r = i >> 8, ci = i & 255; dst[i] = w[ci * 3 + r]; }
}

// ---------------- MFMA rows-GEMM: C = A_rows @ Bt^T + bias ----------------
// A bf16 rows (K contiguous); Bt[N][Kpad] bf16 (output-channel-major, k contiguous).
// 64x64 tile, 4 waves; wave w owns rows w*16..+16, all 64 cols (4 MFMA col-tiles).
// mfma_f32_16x16x32_bf16: A frag lane l: row l&15, k (l>>4)*8..+8 (one b128 load);
// C/D: col = lane&15, row = (lane>>4)*4 + reg  [m89 verified].
// SPLIT: Bt2 holds bf16 residual (w - bf16(w)); 2x MFMA per col-tile -> ~fp32 weight precision.
template <typename CT, bool SPLIT>
__global__ __launch_bounds__(256) void gemm_mfma_kernel(
    const u16* __restrict__ A, const u16* __restrict__ Bt, const u16* __restrict__ Bt2,
    const float* __restrict__ bias, CT* __restrict__ C,
    int N, int Kpad, int Mb,
    long aBatchStride, int aRowStride,
    long cBatchStride, int cRowStride, int relu) {
  int tid = threadIdx.x;
  int wave = tid >> 6, lane = tid & 63;
  int lrow = lane & 15, lk = (lane >> 4) * 8;
  int row0 = blockIdx.x * 64 + wave * 16;
  int col0 = blockIdx.y * 64;
  int grow = row0 + lrow;
  int b_ = grow / Mb, m_ = grow - b_ * Mb;
  const u16* arow = A + (long)b_ * aBatchStride + (long)m_ * aRowStride + lk;
  const u16* bp0 = Bt + (long)(col0 + lrow) * Kpad + lk;
  const u16* bq0 = SPLIT ? (Bt2 + (long)(col0 + lrow) * Kpad + lk) : bp0;
  f32x4 acc0 = {0.f, 0.f, 0.f, 0.f};
  f32x4 acc1 = acc0, acc2 = acc0, acc3 = acc0;
  for (int kk = 0; kk < Kpad; kk += 32) {
    s16x8 av = *(const s16x8*)(arow + kk);
    acc0 = __builtin_amdgcn_mfma_f32_16x16x32_bf16(av, *(const s16x8*)(bp0 + kk), acc0, 0, 0, 0);
    acc1 = __builtin_amdgcn_mfma_f32_16x16x32_bf16(av, *(const s16x8*)(bp0 + 16L * Kpad + kk), acc1, 0, 0, 0);
    acc2 = __builtin_amdgcn_mfma_f32_16x16x32_bf16(av, *(const s16x8*)(bp0 + 32L * Kpad + kk), acc2, 0, 0, 0);
    acc3 = __builtin_amdgcn_mfma_f32_16x16x32_bf16(av, *(const s16x8*)(bp0 + 48L * Kpad + kk), acc3, 0, 0, 0);
    if (SPLIT) {
      acc0 = __builtin_amdgcn_mfma_f32_16x16x32_bf16(av, *(const s16x8*)(bq0 + kk), acc0, 0, 0, 0);
      acc1 = __builtin_amdgcn_mfma_f32_16x16x32_bf16(av, *(const s16x8*)(bq0 + 16L * Kpad + kk), acc1, 0, 0, 0);
      acc2 = __builtin_amdgcn_mfma_f32_16x16x32_bf16(av, *(const s16x8*)(bq0 + 32L * Kpad + kk), acc2, 0, 0, 0);
      acc3 = __builtin_amdgcn_mfma_f32_16x16x32_bf16(av, *(const s16x8*)(bq0 + 48L * Kpad + kk), acc3, 0, 0, 0);
    }
  }
  int erow = row0 + (lane >> 4) * 4;
  int b2 = erow / Mb, m2 = erow - b2 * Mb;
  CT* cbase = C + (long)b2 * cBatchStride + (long)m2 * cRowStride + col0 + lrow;
#define EPI(cc, accv) { \
    float bv = bias[col0 + (cc) * 16 + lrow]; \
    float v0 = accv[0] + bv, v1 = accv[1] + bv, v2 = accv[2] + bv, v3 = accv[3] + bv; \
    if (relu) { v0 = fmaxf(v0, 0.f); v1 = fmaxf(v1, 0.f); v2 = fmaxf(v2, 0.f); v3 = fmaxf(v3, 0.f); } \
    stc(cbase + 0L * cRowStride + (cc) * 16, v0); \
    stc(cbase + 1L * cRowStride + (cc) * 16, v1); \
    stc(cbase + 2L * cRowStride + (cc) * 16, v2); \
    stc(cbase + 3L * cRowStride + (cc) * 16, v3); }
  EPI(0, acc0) EPI(1, acc1) EPI(2, acc2) EPI(3, acc3)
#undef EPI
}

// ---------------- note-segment scan: parallel runs-scan ----------------
__global__ __launch_bounds__(256) void seg_scan_kernel(const int* __restrict__ seq,
                                int* __restrict__ nstart, int* __restrict__ nlen) {
  __shared__ unsigned char v[P_];
  __shared__ int sc[2][256];
  int b = blockIdx.x, tid = threadIdx.x;
  for (int i = tid; i < P_; i += 256) {
    int s = seq[(long)b * P_ + i];
    v[i] = (s > 1 && i != P_ - 1) ? 1 : 0;   // last position never included
  }
  for (int n = tid; n < N_; n += 256) { nstart[b * N_ + n] = 0; nlen[b * N_ + n] = 0; }
  __syncthreads();
  int base = tid << 4;
  int c = 0;
#pragma unroll
  for (int i = 0; i < 16; i++) {
    int p = base + i;
    int val = v[p];
    int prev = p ? v[p - 1] : 0;
    c += val & (prev ^ 1);
  }
  sc[0][tid] = c;
  __syncthreads();
  int cur = 0;
  for (int d = 1; d < 256; d <<= 1) {
    int x = sc[cur][tid];
    if (tid >= d) x += sc[cur][tid - d];
    sc[cur ^ 1][tid] = x;
    cur ^= 1;
    __syncthreads();
  }
  int sg = tid ? sc[cur][tid - 1] : 0;
  for (int i = 0; i < 16; i++) {
    int p = base + i;
    int val = v[p];
    int prev = p ? v[p - 1] : 0;
    if (val && !prev) {
      if (sg < N_) {
        int len = 0, q = p;
        while (q < P_ && v[q]) { len++; q++; }
        nstart[b * N_ + sg] = p;
        nlen[b * N_ + sg] = len;
      }
      sg++;
    }
  }
}

// ---------------- segment mean + enc (bf16 in/out, stride 288) ----------------
__global__ __launch_bounds__(256) void agg_enc_kernel(
    const u16* __restrict__ X2b, const int* __restrict__ nstart, const int* __restrict__ nlen,
    const float* __restrict__ dur, u16* __restrict__ enc, int b0) {
  int n = blockIdx.x, gb = blockIdx.y;
  int b = b0 + gb;
  int d = threadIdx.x;
  int len = nlen[b * N_ + n], st = nstart[b * N_ + n];
  float acc = 0.f;
  for (int i = 0; i < len; i++) acc += bf2f(X2b[((long)gb * PP + st + 1 + i) * 256 + d]);
  float m = (len > 0) ? acc / (float)len : 0.f;
  long e = ((long)b * N_ + n) * ENCS;
  enc[e + d] = f2bf(m);
  if (d == 0) {
    float dd = dur[b * N_ + n];
    enc[e + 256] = f2bf(dd);
    enc[e + 257] = f2bf(1.f / (dd + 1.f));
  }
  if (d >= 2 && d < 32) enc[e + 256 + d] = 0;  // zero tail 258..287
}

// ---------------- LSTM recurrence (round-6 form: LDS h-broadcast, pinned regs) ----------------
#define REC_LDS_BYTES (131072 + 4096 + 1024)
__global__ __attribute__((amdgpu_waves_per_eu(2, 2))) __launch_bounds__(512)
void lstm_rec2_kernel(
    const float* __restrict__ Z,      // [2][32][TCH][1024] fp32, permuted cols
    const u32x4* __restrict__ Wv,     // [2][2][24][512] fp16 quads (k<192)
    const u32x4* __restrict__ Ws,     // [2][2][8][512] fp16 quads (k>=192)
    float* __restrict__ state,        // [64][2][256]
    u16* __restrict__ Y, int yRowsPerB, int yPad, int r) {
  extern __shared__ char smem[];
  u32x4* WL = (u32x4*)smem;                              // 8192 quads
  float* zb = (float*)(smem + 131072);                   // 1024 f32
  u16*   hb = (u16*)(smem + 131072 + 4096);              // 256 fp16
  const u32x4* hb4 = (const u32x4*)hb;                   // 32 quads

  int chain = blockIdx.x;
  int d = chain >> 5, b = chain & 31;
  int tid = threadIdx.x;
  const float* Zb = Z + (long)(d * 32 + b) * (TCH * 1024);

  for (int iq = 0; iq < 16; ++iq) {
    int q = iq * 512 + tid;
    WL[q] = Ws[(long)d * 8192 + q];
  }
  const u32x4* WvD = Wv + (long)d * 2 * 24 * 512;
#define DECLW(i) u32x4 wA##i, wB##i;
  REP24(DECLW)
#undef DECLW
#define LOADW(i) wA##i = WvD[(i) * 512 + tid]; wB##i = WvD[(24 + (i)) * 512 + tid];
  REP24(LOADW)
#undef LOADW
#define PINW(i) asm volatile("" : "+v"(wA##i), "+v"(wB##i));
  REP24(PINW)
#undef PINW

  float h_reg = 0.f, c_reg = 0.f;
  if (tid < 256) {
    if (r > 0) {
      h_reg = state[(chain * 2 + 0) * 256 + tid];
      c_reg = state[(chain * 2 + 1) * 256 + tid];
    }
    hb[tid] = f2h_bits(h_reg);
  }
  __syncthreads();

  int t0 = (d == 0) ? r * TCH : (NTCH - 1 - r) * TCH;
  int tcf = d ? (TCH - 1) : 0;
  float preA = Zb[(long)tcf * 1024 + tid];
  float preB = Zb[(long)tcf * 1024 + 512 + tid];

  for (int tt = 0; tt < TCH; ++tt) {
    float accA = preA, accB = preB;
    if (tt + 1 < TCH) {
      int tc2 = d ? (TCH - 2 - tt) : (tt + 1);
      preA = Zb[(long)tc2 * 1024 + tid];
      preB = Zb[(long)tc2 * 1024 + 512 + tid];
    }
#define MACW(i) { u32x4 hq = hb4[i]; DOT4(accA, wA##i, hq); DOT4(accB, wB##i, hq); }
    REP24(MACW)
#undef MACW
#define MACL(i) { u32x4 hq = hb4[24 + (i)]; \
                  u32x4 qa = WL[(i) * 512 + tid]; \
                  u32x4 qb = WL[4096 + (i) * 512 + tid]; \
                  DOT4(accA, qa, hq); DOT4(accB, qb, hq); }
    REP8(MACL)
#undef MACL
    zb[tid] = accA;
    zb[tid + 512] = accB;
    __syncthreads();
    int tcur = d ? (TCH - 1 - tt) : tt;
    if (tid < 256) {
      float4 z4 = *(const float4*)&zb[tid * 4];   // (i,f,g,o) of unit tid
      float ig = sigmoidf_(z4.x), fg = sigmoidf_(z4.y);
      float gg = tanhf_(z4.z), og = sigmoidf_(z4.w);
      c_reg = fg * c_reg + ig * gg;
      float h = og * tanhf_(c_reg);
      h_reg = h;
      hb[tid] = f2h_bits(h);
      Y[((long)b * yRowsPerB + t0 + tcur + yPad) * 512 + d * 256 + tid] = f2bf(h);
    }
    __syncthreads();
  }
  if (r != NTCH - 1 && tid < 256) {
    state[(chain * 2 + 0) * 256 + tid] = h_reg;
    state[(chain * 2 + 1) * 256 + tid] = c_reg;
  }
}

// ---------------- final conv (Cout=1): wave per row ----------------
__global__ __launch_bounds__(256) void conv4_kernel(
    const float* __restrict__ C3p, const float* __restrict__ w,
    const float* __restrict__ b2, float* __restrict__ out) {
  int row = blockIdx.x * 4 + (threadIdx.x >> 6);
  int lane = threadIdx.x & 63;
  int b = row >> 10, t = row & (N_ - 1);
  const float* a = C3p + ((long)b * NP + t) * 256;
  float acc = 0.f;
  for (int k = lane; k < 768; k += 64) acc += a[k] * w[k];
  for (int off = 32; off; off >>= 1) acc += __shfl_down(acc, off, 64);
  if (lane == 0) out[row] = acc + b2[0];
}

// ---------------- host launcher ----------------
extern "C" void kernel_launch(void* const* d_in, const int* in_sizes, int n_in,
                              void* d_out, int out_size, void* d_ws, size_t ws_size,
                              hipStream_t stream) {
  const float* dur     = (const float*)d_in[0];
  const int*   seq     = (const int*)d_in[1];
  const int*   order   = (const int*)d_in[2];
  const float* emb     = (const float*)d_in[3];
  const float* pos_emb = (const float*)d_in[4];
  const float* mix_w1  = (const float*)d_in[5];
  const float* mix_b1  = (const float*)d_in[6];
  const float* mix_w2  = (const float*)d_in[7];
  const float* mix_b2  = (const float*)d_in[8];
  const float* wih0    = (const float*)d_in[9];
  const float* whh0    = (const float*)d_in[10];
  const float* bih0    = (const float*)d_in[11];
  const float* bhh0    = (const float*)d_in[12];
  const float* wih1    = (const float*)d_in[13];
  const float* whh1    = (const float*)d_in[14];
  const float* bih1    = (const float*)d_in[15];
  const float* bhh1    = (const float*)d_in[16];
  const float* cnn_w1  = (const float*)d_in[17];
  const float* cnn_b1  = (const float*)d_in[18];
  const float* cnn_w2  = (const float*)d_in[19];
  const float* cnn_b2  = (const float*)d_in[20];
  float* out = (float*)d_out;
  float* ws = (float*)d_ws;

  (void)hipFuncSetAttribute((const void*)lstm_rec2_kernel,
                            hipFuncAttributeMaxDynamicSharedMemorySize, REC_LDS_BYTES);

  // ---- workspace layout (float units, 16-aligned) ----
  const long X0B_F = (long)GB * PP * X0S / 2;   // bf16 halves
  const long X1B_F = (long)GB * PP * 256 / 2;
  const long X2B_F = X1B_F;
  const long Z_E   = 2L * B_ * TCH * 1024;
  const long C3P_E = (long)B_ * NP * 256;
  long region = X0B_F + X1B_F + X2B_F;
  if (Z_E > region) region = Z_E;
  if (C3P_E > region) region = C3P_E;

  long off = 0;
  auto alloc = [&](long n) { long ret = off; off += (n + 15) & ~15L; return ret; };
  long o_region = alloc(region);
  long o_enc    = alloc((long)B_ * N_ * ENCS / 2);
  long o_Y0     = alloc((long)B_ * N_ * 512 / 2);
  long o_Y1p    = alloc((long)B_ * NP * 512 / 2);
  long o_W1h    = alloc(256L * 832 / 2);
  long o_W2h    = alloc(256L * 768 / 2);
  long o_Wc1h   = alloc(256L * 1536 / 2);
  long o_Wc1l   = alloc(256L * 1536 / 2);
  long o_Wc2r   = alloc(768);
  long o_Wih0h  = alloc(2L * 1024 * ENCS / 2);
  long o_Wih0l  = alloc(2L * 1024 * ENCS / 2);
  long o_Wih1h  = alloc(2L * 1024 * 512 / 2);
  long o_Wih1l  = alloc(2L * 1024 * 512 / 2);
  long o_Wv0    = alloc(49152L * 4);
  long o_Ws0    = alloc(16384L * 4);
  long o_Wv1    = alloc(49152L * 4);
  long o_Ws1    = alloc(16384L * 4);
  long o_bs0    = alloc(2048);
  long o_bs1    = alloc(2048);
  long o_state  = alloc(64L * 2 * 256);
  long o_nst    = alloc((long)B_ * N_);
  long o_nln    = alloc((long)B_ * N_);

  if ((size_t)(off * 4) > ws_size) {
    float v = -(1000.0f + (float)(ws_size >> 20));
    fill_sentinel_kernel<<<(out_size + 255) / 256, 256, 0, stream>>>(out, out_size, v);
    return;
  }

  u16*   X0b  = (u16*)(ws + o_region);
  u16*   X1b  = (u16*)(ws + o_region + X0B_F);
  u16*   X2b  = (u16*)(ws + o_region + X0B_F + X1B_F);
  float* Z    = ws + o_region;              // alias (after phase A)
  float* C3p  = ws + o_region;              // alias (after recs)
  u16*   enc  = (u16*)(ws + o_enc);
  u16*   Y0   = (u16*)(ws + o_Y0);
  u16*   Y1p  = (u16*)(ws + o_Y1p);
  u16*   W1h  = (u16*)(ws + o_W1h);
  u16*   W2h  = (u16*)(ws + o_W2h);
  u16*   Wc1h = (u16*)(ws + o_Wc1h);
  u16*   Wc1l = (u16*)(ws + o_Wc1l);
  float* Wc2r = ws + o_Wc2r;
  u16*   Wih0h = (u16*)(ws + o_Wih0h);
  u16*   Wih0l = (u16*)(ws + o_Wih0l);
  u16*   Wih1h = (u16*)(ws + o_Wih1h);
  u16*   Wih1l = (u16*)(ws + o_Wih1l);
  uint4* Wv0  = (uint4*)(ws + o_Wv0);
  uint4* Ws0  = (uint4*)(ws + o_Ws0);
  uint4* Wv1  = (uint4*)(ws + o_Wv1);
  uint4* Ws1  = (uint4*)(ws + o_Ws1);
  float* bs0  = ws + o_bs0;
  float* bs1  = ws + o_bs1;
  float* state = ws + o_state;
  int* nstart = (int*)(ws + o_nst);
  int* nlen   = (int*)(ws + o_nln);

  // ---- repacks / setup ----
  zero_bf_guards_kernel<<<GB, 256, 0, stream>>>(X0b, X1b);
  zero_y1p_guards_kernel<<<B_, 256, 0, stream>>>(Y1p);
  repack_conv_bt_kernel<<<(int)((256L * 832 + 255) / 256), 256, 0, stream>>>(
      mix_w1, W1h, nullptr, 266, X0S, 832, 256);
  repack_conv_bt_kernel<<<(int)((256L * 768 + 255) / 256), 256, 0, stream>>>(
      mix_w2, W2h, nullptr, 256, 256, 768, 256);
  repack_conv_bt_kernel<<<(int)((256L * 1536 + 255) / 256), 256, 0, stream>>>(
      cnn_w1, Wc1h, Wc1l, 512, 512, 1536, 256);
  repack_conv4_w_kernel<<<3, 256, 0, stream>>>(cnn_w2, Wc2r);
  for (int d = 0; d < 2; d++) {
    repack_dense_bt_kernel<<<(int)((1024L * ENCS + 255) / 256), 256, 0, stream>>>(
        wih0 + (long)d * 1024 * 258, Wih0h + (long)d * 1024 * ENCS,
        Wih0l + (long)d * 1024 * ENCS, 258, ENCS);
    repack_dense_bt_kernel<<<(int)((1024L * 512 + 255) / 256), 256, 0, stream>>>(
        wih1 + (long)d * 1024 * 512, Wih1h + (long)d * 1024 * 512,
        Wih1l + (long)d * 1024 * 512, 512, 512);
  }
  repack_whh_reg_kernel<<<192, 256, 0, stream>>>(whh0, Wv0);
  repack_whh_lds_kernel<<<64, 256, 0, stream>>>(whh0, Ws0);
  repack_whh_reg_kernel<<<192, 256, 0, stream>>>(whh1, Wv1);
  repack_whh_lds_kernel<<<64, 256, 0, stream>>>(whh1, Ws1);
  bias_sum_perm_kernel<<<8, 256, 0, stream>>>(bih0, bhh0, bs0);
  bias_sum_perm_kernel<<<8, 256, 0, stream>>>(bih1, bhh1, bs1);
  seg_scan_kernel<<<B_, 256, 0, stream>>>(seq, nstart, nlen);

  // ---- phase A: embed -> conv1 -> conv2 -> aggregate (8-batch chunks) ----
  for (int ch = 0; ch < NCHK; ch++) {
    int b0 = ch * GB;
    long total = (long)GB * P_ * X0S;
    embed_bf16_kernel<<<(int)((total + 255) / 256), 256, 0, stream>>>(seq, order, emb, pos_emb, X0b, b0);
    gemm_mfma_kernel<u16, false><<<dim3(GB * P_ / 64, 4), 256, 0, stream>>>(
        X0b, W1h, nullptr, mix_b1, X1b + 256,
        256, 832, P_, (long)PP * X0S, X0S, (long)PP * 256, 256, 1);
    gemm_mfma_kernel<u16, false><<<dim3(GB * P_ / 64, 4), 256, 0, stream>>>(
        X1b, W2h, nullptr, mix_b2, X2b + 256,
        256, 768, P_, (long)PP * 256, 256, (long)PP * 256, 256, 0);
    agg_enc_kernel<<<dim3(N_, GB), 256, 0, stream>>>(X2b, nstart, nlen, dur, enc, b0);
  }

  // ---- LSTM layers (time-chunked Z: MFMA x-proj + CU-resident rec) ----
  const long ZD = (long)B_ * TCH * 1024;
  for (int layer = 0; layer < 2; layer++) {
    const u16*  Xl   = (layer == 0) ? enc : Y0;
    int         Kp   = (layer == 0) ? ENCS : 512;
    const u16*  Wh   = (layer == 0) ? Wih0h : Wih1h;
    const u16*  Wl   = (layer == 0) ? Wih0l : Wih1l;
    long        WihD = (long)1024 * Kp;
    const float* bsl = (layer == 0) ? bs0 : bs1;
    const u32x4* Wv  = (const u32x4*)((layer == 0) ? Wv0 : Wv1);
    const u32x4* Wsp = (const u32x4*)((layer == 0) ? Ws0 : Ws1);
    u16*        Yl   = (layer == 0) ? Y0 : Y1p;
    int         yRows = (layer == 0) ? N_ : NP;
    int         yPad  = (layer == 0) ? 0 : 1;
    for (int r = 0; r < NTCH; r++) {
      for (int d = 0; d < 2; d++) {
        int t0 = (d == 0) ? r * TCH : (NTCH - 1 - r) * TCH;
        gemm_mfma_kernel<float, true><<<dim3(B_ * TCH / 64, 16), 256, 0, stream>>>(
            Xl + (long)t0 * Kp, Wh + (long)d * WihD, Wl + (long)d * WihD,
            bsl + d * 1024, Z + d * ZD,
            1024, Kp, TCH, (long)N_ * Kp, Kp, (long)TCH * 1024, 1024, 0);
      }
      lstm_rec2_kernel<<<64, 512, REC_LDS_BYTES, stream>>>(Z, Wv, Wsp, state, Yl, yRows, yPad, r);
    }
  }

  // ---- head: MFMA conv(relu) K=1536 (split weights), then 1-channel conv ----
  zero_c3p_guards_kernel<<<B_, 256, 0, stream>>>(C3p);
  gemm_mfma_kernel<float, true><<<dim3(B_ * N_ / 64, 4), 256, 0, stream>>>(
      Y1p, Wc1h, Wc1l, cnn_b1, C3p + 256,
      256, 1536, N_, (long)NP * 512, 512, (long)NP * 256, 256, 1);
  conv4_kernel<<<B_ * N_ / 4, 256, 0, stream>>>(C3p, Wc2r, cnn_b2, out);
}